// Round 1
// 320.881 us; speedup vs baseline: 1.0262x; 1.0262x over previous
//
#include <hip/hip_runtime.h>

#define KMAX 17            // edges per thread in count/scatter
#define CTH  256           // threads per count/scatter block
#define EVB  (KMAX * CTH)  // 4352 events per block

__device__ __forceinline__ unsigned short f2bf(float x) {   // RNE
    unsigned u = __float_as_uint(x);
    u += 0x7FFF + ((u >> 16) & 1);
    return (unsigned short)(u >> 16);
}

// ---------------- count events per (bucket, block) ----------------
__global__ __launch_bounds__(CTH) void k_count(const int* __restrict__ src,
        const int* __restrict__ dst, int* __restrict__ tab,
        int E, int NBK, int NBC) {
    __shared__ int cS[512], cD[512];
    const int t = threadIdx.x;
    for (int i = t; i < 512; i += CTH) { cS[i] = 0; cD[i] = 0; }
    __syncthreads();
    const int e0 = blockIdx.x * EVB;
    int e1 = e0 + EVB; if (e1 > E) e1 = E;
    for (int e = e0 + t; e < e1; e += CTH) {
        atomicAdd(&cS[src[e] >> 8], 1);
        atomicAdd(&cD[dst[e] >> 8], 1);
    }
    __syncthreads();
    const int col = (blockIdx.x & 7) * (NBC >> 3) + (blockIdx.x >> 3);
    for (int b = t; b < NBK; b += CTH) {
        tab[(size_t)b * NBC + col]         = cS[b];
        tab[(size_t)(NBK + b) * NBC + col] = cD[b];
    }
}

// ---------------- hierarchical exclusive scan (3 phases) ----------------
__global__ __launch_bounds__(256) void k_scanA(const int* __restrict__ tab,
                                               int* __restrict__ bsum, int Ntab) {
    __shared__ int red[256];
    const int t = threadIdx.x;
    const int base = blockIdx.x * 2048 + t * 8;
    int s = 0;
#pragma unroll
    for (int k = 0; k < 8; ++k) { int i = base + k; if (i < Ntab) s += tab[i]; }
    red[t] = s; __syncthreads();
    for (int off = 128; off > 0; off >>= 1) {
        if (t < off) red[t] += red[t + off];
        __syncthreads();
    }
    if (t == 0) bsum[blockIdx.x] = red[0];
}

__global__ __launch_bounds__(256) void k_scanB(int* __restrict__ bsum, int NB) {
    __shared__ int sc[256];
    __shared__ int carry;
    const int t = threadIdx.x;
    if (t == 0) carry = 0;
    __syncthreads();
    for (int base = 0; base < NB; base += 256) {
        const int i = base + t;
        const int v = (i < NB) ? bsum[i] : 0;
        sc[t] = v; __syncthreads();
        for (int off = 1; off < 256; off <<= 1) {
            int add = (t >= off) ? sc[t - off] : 0;
            __syncthreads();
            sc[t] += add;
            __syncthreads();
        }
        if (i < NB) bsum[i] = carry + sc[t] - v;   // exclusive
        __syncthreads();
        if (t == 255) carry += sc[255];
        __syncthreads();
    }
}

__global__ __launch_bounds__(256) void k_scanC(int* __restrict__ tab,
                                               const int* __restrict__ bsum, int Ntab) {
    __shared__ int sc[256];
    const int t = threadIdx.x;
    const int base = blockIdx.x * 2048 + t * 8;
    int v[8]; int s = 0;
#pragma unroll
    for (int k = 0; k < 8; ++k) { int i = base + k; v[k] = (i < Ntab) ? tab[i] : 0; s += v[k]; }
    sc[t] = s; __syncthreads();
    for (int off = 1; off < 256; off <<= 1) {
        int add = (t >= off) ? sc[t - off] : 0;
        __syncthreads();
        sc[t] += add;
        __syncthreads();
    }
    int run = bsum[blockIdx.x] + sc[t] - s;
#pragma unroll
    for (int k = 0; k < 8; ++k) {
        int i = base + k;
        if (i < Ntab) { tab[i] = run; run += v[k]; }
    }
    if (base < Ntab && Ntab <= base + 8) tab[Ntab] = run;   // sentinel = 2E
}

// ---------------- scatter: LDS-staged, bucket-ordered dump ----------------
__global__ __launch_bounds__(CTH) void k_scatter(const int* __restrict__ src,
        const int* __restrict__ dst, const int* __restrict__ tab,
        unsigned char* __restrict__ srecs, unsigned* __restrict__ drecs,
        int E, int NBK, int NBC) {
    __shared__ unsigned dstage[EVB];          // 17.4 KB
    __shared__ unsigned char sstage[EVB];     // 4.4 KB
    __shared__ unsigned off[513];             // packed exclusive offsets
    __shared__ unsigned pos[512];             // packed running counters
    __shared__ int bS[512], bD[512];
    __shared__ unsigned red[256];
    const int t = threadIdx.x;
    pos[t] = 0; pos[t + 256] = 0;
    __syncthreads();
    const int e0 = blockIdx.x * EVB;
    const int e1full = e0 + EVB;
    const int e1 = (e1full > E) ? E : e1full;

    int sv[KMAX], dv[KMAX];
#pragma unroll
    for (int k = 0; k < KMAX; ++k) {
        const int e = e0 + k * CTH + t;
        if (e < e1) {
            sv[k] = src[e]; dv[k] = dst[e];
            atomicAdd(&pos[sv[k] >> 8], 1u);
            atomicAdd(&pos[dv[k] >> 8], 0x10000u);
        }
    }
    __syncthreads();
    const unsigned v0 = pos[2 * t], v1 = pos[2 * t + 1];
    const unsigned ps = v0 + v1;
    red[t] = ps;
    __syncthreads();
    for (int o = 1; o < 256; o <<= 1) {
        unsigned add = (t >= o) ? red[t - o] : 0;
        __syncthreads();
        red[t] += add;
        __syncthreads();
    }
    const unsigned base = red[t] - ps;
    off[2 * t] = base;
    off[2 * t + 1] = base + v0;
    if (t == 255) off[512] = red[255];
    __syncthreads();
    pos[t] = off[t]; pos[t + 256] = off[t + 256];
    __syncthreads();
#pragma unroll
    for (int k = 0; k < KMAX; ++k) {
        const int e = e0 + k * CTH + t;
        if (e < e1) {
            const int s = sv[k], d = dv[k];
            const unsigned rs = atomicAdd(&pos[s >> 8], 1u);
            sstage[rs & 0xFFFFu] = (unsigned char)(s & 255);
            const unsigned rd = atomicAdd(&pos[d >> 8], 0x10000u);
            dstage[rd >> 16] = ((unsigned)s << 8) | (unsigned)(d & 255);
        }
    }
    const int col = (blockIdx.x & 7) * (NBC >> 3) + (blockIdx.x >> 3);
    for (int b = t; b < NBK; b += CTH) {
        bS[b] = tab[(size_t)b * NBC + col];
        bD[b] = tab[(size_t)(NBK + b) * NBC + col] - E;
    }
    __syncthreads();
    const int tot = e1 - e0;
    for (int slot = t; slot < tot; slot += CTH) {       // srecs dump
        int lo = 0, hi = NBK;
        while (hi - lo > 1) {
            const int md = (lo + hi) >> 1;
            if ((off[md] & 0xFFFFu) <= (unsigned)slot) lo = md; else hi = md;
        }
        srecs[bS[lo] + slot - (int)(off[lo] & 0xFFFFu)] = sstage[slot];
    }
    for (int slot = t; slot < tot; slot += CTH) {       // drecs dump
        int lo = 0, hi = NBK;
        while (hi - lo > 1) {
            const int md = (lo + hi) >> 1;
            if ((off[md] >> 16) <= (unsigned)slot) lo = md; else hi = md;
        }
        drecs[bD[lo] + slot - (int)(off[lo] >> 16)] = dstage[slot];
    }
}

// ---------------- partial degree counts: 4 sub-blocks per bucket ----------------
__global__ __launch_bounds__(256) void k_degA(const unsigned char* __restrict__ srecs,
        const unsigned* __restrict__ drecs, const int* __restrict__ tab,
        unsigned* __restrict__ pdeg, int NBK, int NBC, int E) {
    __shared__ int oc[256], ic[256];
    const int b = blockIdx.x >> 2, s = blockIdx.x & 3;
    const int t = threadIdx.x;
    oc[t] = 0; ic[t] = 0;
    __syncthreads();
    const int sA0 = tab[(size_t)b * NBC];
    const int sA1 = tab[(size_t)(b + 1) * NBC];
    const int dA0 = tab[(size_t)(NBK + b) * NBC] - E;
    const int dA1 = tab[(size_t)(NBK + b + 1) * NBC] - E;
    const int sl = sA1 - sA0, dl = dA1 - dA0;
    const int s0 = sA0 + (sl * s) / 4, s1 = sA0 + (sl * (s + 1)) / 4;
    const int d0 = dA0 + (dl * s) / 4, d1 = dA0 + (dl * (s + 1)) / 4;
    for (int i = s0 + t; i < s1; i += 256) atomicAdd(&oc[srecs[i]], 1);
    for (int i = d0 + t; i < d1; i += 256) atomicAdd(&ic[drecs[i] & 255], 1);
    __syncthreads();
    pdeg[(size_t)blockIdx.x * 256 + t] = (unsigned)oc[t] | ((unsigned)ic[t] << 16);
}

// ---------------- projection + degree fold: barrier-free wave GEMV ----------------
// 64 rows/block, 4 lanes per row split K 4 ways. Lane q owns columns
// 64j + 16f + 4q + e (j,f,e in 0..3): per-quad global loads are 64B
// contiguous (coalesced), all 16 dwordx4 issued before the single barrier.
// W staged once into LDS with stride-20 rows: simultaneous quad reads land
// 16 banks apart (2-way conflict = free; natural stride 16 would be 4-way).
// No __syncthreads in the compute loop -> waves run fully autonomously and
// latency is hidden by 16 in-flight loads/wave instead of a barrier pipeline.
__device__ __forceinline__ void quadred(float4& v) {
    v.x += __shfl_xor(v.x, 1); v.x += __shfl_xor(v.x, 2);
    v.y += __shfl_xor(v.y, 1); v.y += __shfl_xor(v.y, 2);
    v.z += __shfl_xor(v.z, 1); v.z += __shfl_xor(v.z, 2);
    v.w += __shfl_xor(v.w, 1); v.w += __shfl_xor(v.w, 2);
}

__global__ __launch_bounds__(256) void k_gemm(const float* __restrict__ X,
                                              const float* __restrict__ W,
                                              const unsigned* __restrict__ pdeg,
                                              float* __restrict__ nd,
                                              unsigned short* __restrict__ Hb, int N) {
    __shared__ __align__(16) float lw[256 * 20 + 16];   // 20.5 KB, stride-20 rows
    __shared__ float lns[64];
    const int t = threadIdx.x;
    const int node0 = blockIdx.x * 64;
    const int r = t >> 2, q = t & 3;
    const int row = node0 + r;
    const bool valid = row < N;

    // issue all 16 X loads first: they fly during W staging + fold + barrier
    float4 xr[4][4];
    if (valid) {
        const float* xp = X + (size_t)row * 256 + 4 * q;
#pragma unroll
        for (int j = 0; j < 4; ++j)
#pragma unroll
            for (int f = 0; f < 4; ++f)
                xr[j][f] = *(const float4*)(xp + 64 * j + 16 * f);
    } else {
#pragma unroll
        for (int j = 0; j < 4; ++j)
#pragma unroll
            for (int f = 0; f < 4; ++f)
                xr[j][f] = float4{0.f, 0.f, 0.f, 0.f};
    }

    // stage W[256][16] -> lw (row stride 20 floats), vectorized
#pragma unroll
    for (int u = 0; u < 4; ++u) {
        const int idx = t + 256 * u;            // float4 index 0..1023
        const int k = idx >> 2, p = idx & 3;
        *(float4*)&lw[k * 20 + 4 * p] = ((const float4*)W)[idx];
    }

    if (t < 64) {   // degree fold (pdeg tiled per 256-node bucket)
        const int node = node0 + t;
        const int bk = node >> 8, w = node & 255;
        int od = 0, idg = 0;
#pragma unroll
        for (int s = 0; s < 4; ++s) {
            const unsigned p = pdeg[(size_t)(bk * 4 + s) * 256 + w];
            od  += (int)(p & 0xFFFFu);
            idg += (int)(p >> 16);
        }
        lns[t] = rsqrtf(fmaxf((float)od, 1.f));
        if (node < N) nd[node] = rsqrtf(fmaxf((float)idg, 1.f));
    }
    __syncthreads();   // the only barrier

    const float* lwq = lw + 80 * q;   // folds lane's k-offset (+4q rows)
    float4 a0{0.f,0.f,0.f,0.f}, a1{0.f,0.f,0.f,0.f};
    float4 a2{0.f,0.f,0.f,0.f}, a3{0.f,0.f,0.f,0.f};
#pragma unroll
    for (int j = 0; j < 4; ++j)
#pragma unroll
        for (int f = 0; f < 4; ++f) {
            const float4 xv = xr[j][f];
#pragma unroll
            for (int e = 0; e < 4; ++e) {
                const float xs = (e == 0) ? xv.x : (e == 1) ? xv.y
                               : (e == 2) ? xv.z : xv.w;
                const float* wr = lwq + (64 * j + 16 * f + e) * 20;
                const float4 w0 = *(const float4*)(wr);
                const float4 w1 = *(const float4*)(wr + 4);
                const float4 w2 = *(const float4*)(wr + 8);
                const float4 w3 = *(const float4*)(wr + 12);
                a0.x += xs * w0.x; a0.y += xs * w0.y; a0.z += xs * w0.z; a0.w += xs * w0.w;
                a1.x += xs * w1.x; a1.y += xs * w1.y; a1.z += xs * w1.z; a1.w += xs * w1.w;
                a2.x += xs * w2.x; a2.y += xs * w2.y; a2.z += xs * w2.z; a2.w += xs * w2.w;
                a3.x += xs * w3.x; a3.y += xs * w3.y; a3.z += xs * w3.z; a3.w += xs * w3.w;
            }
        }

    // quad reduction over the 4 K-splits; then lane q keeps c-group q
    quadred(a0); quadred(a1); quadred(a2); quadred(a3);
    const float4 res = (q == 0) ? a0 : (q == 1) ? a1 : (q == 2) ? a2 : a3;

    if (valid) {
        const float norm = lns[r];
        ushort4 o;
        o.x = f2bf(res.x * norm); o.y = f2bf(res.y * norm);
        o.z = f2bf(res.z * norm); o.w = f2bf(res.w * norm);
        *(ushort4*)&Hb[(size_t)row * 16 + 4 * q] = o;   // 8B/lane, coalesced
    }
}

// ---------------- per-bucket edge accumulation in REGISTERS ----------------
__global__ __launch_bounds__(256) void k_gaccum(const unsigned* __restrict__ drecs,
        const int* __restrict__ tab, const int* __restrict__ seg,
        const float* __restrict__ nd, const unsigned short* __restrict__ Hb,
        float* __restrict__ outagg, int N, int NBK, int NBC, int E, int G) {
    __shared__ float lnd[256];
    __shared__ int   lgi[256];
    __shared__ float lhist[256];
    __shared__ float wred[4 * 48];
    const int b = blockIdx.x >> 1, half = blockIdx.x & 1;
    const int t = threadIdx.x;
    const int node0 = b << 8;
    const int gf = seg[node0];
    lhist[t] = 0.f;
    const int node = node0 + t;
    if (node < N) {
        lnd[t] = nd[node];
        lgi[t] = seg[node] - gf;
    }
    __syncthreads();
    const int dA0 = tab[(size_t)(NBK + b) * NBC] - E;
    const int dA1 = tab[(size_t)(NBK + b + 1) * NBC] - E;
    const int mid = dA0 + ((dA1 - dA0) >> 1);
    const int i0 = half ? mid : dA0;
    const int i1 = half ? dA1 : mid;

    float a0[16], a1[16], a2[16];
#pragma unroll
    for (int j = 0; j < 16; ++j) { a0[j] = 0.f; a1[j] = 0.f; a2[j] = 0.f; }

    for (int i = i0 + t; i < i1; i += 256) {
        const unsigned r = drecs[i];
        const int dlow = r & 255;
        const int s = (int)(r >> 8);
        const float w = lnd[dlow];
        const int gi = lgi[dlow];
        const uint4* hp = (const uint4*)(Hb + (size_t)s * 16);
        const uint4 h0 = hp[0];
        const uint4 h1 = hp[1];
        if (gi < 3) {
            const float w0 = (gi == 0) ? w : 0.f;
            const float w1 = (gi == 1) ? w : 0.f;
            const float w2 = (gi == 2) ? w : 0.f;
#define ACC2(u, j0) { \
            float vlo = __uint_as_float((u) << 16); \
            float vhi = __uint_as_float((u) & 0xFFFF0000u); \
            a0[j0] += vlo * w0; a1[j0] += vlo * w1; a2[j0] += vlo * w2; \
            a0[j0+1] += vhi * w0; a1[j0+1] += vhi * w1; a2[j0+1] += vhi * w2; }
            ACC2(h0.x, 0) ACC2(h0.y, 2) ACC2(h0.z, 4) ACC2(h0.w, 6)
            ACC2(h1.x, 8) ACC2(h1.y, 10) ACC2(h1.z, 12) ACC2(h1.w, 14)
#undef ACC2
        } else {
            const unsigned hw[8] = {h0.x, h0.y, h0.z, h0.w, h1.x, h1.y, h1.z, h1.w};
            if (gi < 16) {
#pragma unroll
                for (int q = 0; q < 8; ++q) {
                    atomicAdd(&lhist[gi * 16 + 2 * q],     __uint_as_float(hw[q] << 16) * w);
                    atomicAdd(&lhist[gi * 16 + 2 * q + 1], __uint_as_float(hw[q] & 0xFFFF0000u) * w);
                }
            } else if (gf + gi < G) {
#pragma unroll
                for (int q = 0; q < 8; ++q) {
                    unsafeAtomicAdd(&outagg[(gf + gi) * 16 + 2 * q],     __uint_as_float(hw[q] << 16) * w);
                    unsafeAtomicAdd(&outagg[(gf + gi) * 16 + 2 * q + 1], __uint_as_float(hw[q] & 0xFFFF0000u) * w);
                }
            }
        }
    }

#pragma unroll
    for (int j = 0; j < 16; ++j) {
#pragma unroll
        for (int off = 32; off > 0; off >>= 1) {
            a0[j] += __shfl_down(a0[j], off, 64);
            a1[j] += __shfl_down(a1[j], off, 64);
            a2[j] += __shfl_down(a2[j], off, 64);
        }
    }
    const int wid = t >> 6, lane = t & 63;
    if (lane == 0) {
#pragma unroll
        for (int j = 0; j < 16; ++j) {
            wred[wid * 48 + j]      = a0[j];
            wred[wid * 48 + 16 + j] = a1[j];
            wred[wid * 48 + 32 + j] = a2[j];
        }
    }
    __syncthreads();
    if (t < 48) {
        const float v = wred[t] + wred[48 + t] + wred[96 + t] + wred[144 + t];
        const int g = gf + t / 16;
        if (v != 0.f && g < G) unsafeAtomicAdd(&outagg[g * 16 + (t & 15)], v);
    } else {
        const float v = lhist[t];
        const int g = gf + t / 16;
        if (v != 0.f && g < G) unsafeAtomicAdd(&outagg[g * 16 + (t & 15)], v);
    }
}

// ---------------- final: gcnt via binary search (seg sorted) ----------------
__global__ void k_final(const float* __restrict__ outagg, const int* __restrict__ seg,
                        const float* __restrict__ bias, float* __restrict__ out,
                        int N, int G) {
    int i = blockIdx.x * 256 + threadIdx.x;
    if (i < G * 16) {
        const int g = i >> 4;
        int lo = 0, hi = N;
        while (lo < hi) { int md = (lo + hi) >> 1; if (seg[md] < g) lo = md + 1; else hi = md; }
        const int a = lo; hi = N;
        while (lo < hi) { int md = (lo + hi) >> 1; if (seg[md] <= g) lo = md + 1; else hi = md; }
        const float cnt = (float)(lo - a);
        out[i] = outagg[i] / fmaxf(cnt, 1.f) + bias[i & 15];
    }
}

extern "C" void kernel_launch(void* const* d_in, const int* in_sizes, int n_in,
                              void* d_out, int out_size, void* d_ws, size_t ws_size,
                              hipStream_t stream) {
    const float* X  = (const float*)d_in[0];
    const float* W  = (const float*)d_in[1];
    const float* bb = (const float*)d_in[2];
    const int* esrc = (const int*)d_in[3];
    const int* edst = (const int*)d_in[4];
    const int* seg  = (const int*)d_in[5];
    const int N = in_sizes[5];                 // 100000
    const int E = in_sizes[3];                 // 3200000
    const int G = out_size / 16;               // 256
    const int NBK = (N + 255) >> 8;            // 391 (<=512 required)
    const int NBC = (((E + EVB - 1) / EVB) + 7) & ~7;   // 736 (x8 for swizzle)
    const int Ntab = 2 * NBK * NBC;            // 575552
    const int NBsc = (Ntab + 2047) / 2048;     // 282 scan blocks

    // ws layout (~20.3 MB; srecs/Hb aliased — srecs dead after k_degA)
    unsigned* drecs = (unsigned*)d_ws;                       // E u32 (12.8 MB)
    int* tab        = (int*)(drecs + (size_t)E);             // Ntab+1 ints (2.3 MB)
    int* bsum       = tab + (Ntab + 1);                      // NBsc (<=1024)
    float* nd       = (float*)(bsum + 1024);                 // N
    float* outagg   = nd + N;                                // G*16  <- memset
    unsigned* pdeg  = (unsigned*)(outagg + (size_t)G * 16);  // NBK*4*256 (1.6 MB)
    unsigned char* srecs = (unsigned char*)(pdeg + (size_t)NBK * 4 * 256); // E bytes \ alias
    unsigned short* Hb   = (unsigned short*)srecs;                          // N*16   / region

    hipMemsetAsync(outagg, 0, (size_t)G * 16 * 4, stream);

    k_count  <<<NBC, CTH, 0, stream>>>(esrc, edst, tab, E, NBK, NBC);
    k_scanA  <<<NBsc, 256, 0, stream>>>(tab, bsum, Ntab);
    k_scanB  <<<1, 256, 0, stream>>>(bsum, NBsc);
    k_scanC  <<<NBsc, 256, 0, stream>>>(tab, bsum, Ntab);
    k_scatter<<<NBC, CTH, 0, stream>>>(esrc, edst, tab, srecs, drecs, E, NBK, NBC);
    k_degA   <<<NBK * 4, 256, 0, stream>>>(srecs, drecs, tab, pdeg, NBK, NBC, E);
    k_gemm   <<<(N + 63) / 64, 256, 0, stream>>>(X, W, pdeg, nd, Hb, N);
    k_gaccum <<<NBK * 2, 256, 0, stream>>>(drecs, tab, seg, nd, Hb, outagg, N, NBK, NBC, E, G);
    k_final  <<<(G * 16 + 255) / 256, 256, 0, stream>>>(outagg, seg, bb, (float*)d_out, N, G);
}